// Round 3
// baseline (896.891 us; speedup 1.0000x reference)
//
#include <hip/hip_runtime.h>
#include <hip/hip_bf16.h>

#define FDIM 128

// ---------------- init: self-loop degree + zero fill cursors ----------------
__global__ void k_init(int* __restrict__ cnt, int* __restrict__ fill, int n) {
    int i = blockIdx.x * 256 + threadIdx.x;
    if (i < n) { cnt[i] = 1; fill[i] = 0; }
}

// ---------------- degree count over edges (row = edge_index[0]) -------------
__global__ void k_count(const int* __restrict__ row, int* __restrict__ cnt, int nE) {
    int stride = gridDim.x * blockDim.x;
    for (int e = blockIdx.x * blockDim.x + threadIdx.x; e < nE; e += stride)
        atomicAdd(&cnt[row[e]], 1);
}

// ---------------- exclusive prefix sum (single block, 1024 threads) ---------
__global__ void k_scan(const int* __restrict__ cnt, int* __restrict__ offs, int n) {
    __shared__ int sd[1024];
    __shared__ int run;
    if (threadIdx.x == 0) run = 0;
    __syncthreads();
    for (int base = 0; base < n; base += 1024) {
        int i = base + threadIdx.x;
        int v = (i < n) ? cnt[i] : 0;
        sd[threadIdx.x] = v;
        __syncthreads();
        for (int off = 1; off < 1024; off <<= 1) {
            int t = (threadIdx.x >= off) ? sd[threadIdx.x - off] : 0;
            __syncthreads();
            sd[threadIdx.x] += t;
            __syncthreads();
        }
        if (i < n) offs[i] = run + sd[threadIdx.x] - v;   // exclusive
        __syncthreads();
        if (threadIdx.x == 1023) run += sd[1023];
        __syncthreads();
    }
    if (threadIdx.x == 0) offs[n] = run;
}

// ---------------- deg^{-1/2} (deg >= 1 always due to self-loop) -------------
__global__ void k_dis(const int* __restrict__ cnt, float* __restrict__ dis, int n) {
    int i = blockIdx.x * 256 + threadIdx.x;
    if (i < n) dis[i] = rsqrtf((float)cnt[i]);
}

// ---------------- CSR fill: bucket col by row (includes self-loops) ---------
__global__ void k_fill(const int* __restrict__ row, const int* __restrict__ col,
                       const int* __restrict__ offs, int* __restrict__ fill,
                       int* __restrict__ sc, int nE, int n) {
    int stride = gridDim.x * blockDim.x;
    int total = nE + n;
    for (int e = blockIdx.x * blockDim.x + threadIdx.x; e < total; e += stride) {
        int r, c;
        if (e < nE) { r = row[e]; c = col[e]; }
        else        { r = e - nE; c = r; }          // self loop
        int pos = offs[r] + atomicAdd(&fill[r], 1);
        sc[pos] = c;
    }
}

// ---------------- support = x @ W  (fp32) -----------------------------------
// Block: 256 threads = 128 features x 2 node-groups; 16 nodes per block.
__global__ void __launch_bounds__(256) k_gemm(const float* __restrict__ x,
                                              const float* __restrict__ w,
                                              float* __restrict__ support, int n) {
    __shared__ float w_s[FDIM * FDIM];   // 64 KB
    __shared__ float x_s[16 * FDIM];     // 8 KB

    const float4* wg = reinterpret_cast<const float4*>(w);
    float4* ws4 = reinterpret_cast<float4*>(w_s);
    #pragma unroll
    for (int it = 0; it < 16; ++it)
        ws4[threadIdx.x + it * 256] = wg[threadIdx.x + it * 256];

    int nb = blockIdx.x * 16;                       // n = 100000 = 6250 * 16
    const float4* xg = reinterpret_cast<const float4*>(x + (size_t)nb * FDIM);
    float4* xs4w = reinterpret_cast<float4*>(x_s);
    #pragma unroll
    for (int it = 0; it < 2; ++it)
        xs4w[threadIdx.x + it * 256] = xg[threadIdx.x + it * 256];
    __syncthreads();

    int f  = threadIdx.x & 127;
    int ng = threadIdx.x >> 7;                      // 0..1 (8 nodes each)
    const float4* xs4 = reinterpret_cast<const float4*>(x_s);
    float acc[8] = {0, 0, 0, 0, 0, 0, 0, 0};
    for (int kg = 0; kg < 32; ++kg) {
        float w0 = w_s[(4 * kg + 0) * FDIM + f];
        float w1 = w_s[(4 * kg + 1) * FDIM + f];
        float w2 = w_s[(4 * kg + 2) * FDIM + f];
        float w3 = w_s[(4 * kg + 3) * FDIM + f];
        #pragma unroll
        for (int j = 0; j < 8; ++j) {
            float4 xv = xs4[(ng * 8 + j) * 32 + kg];   // wave-uniform -> broadcast
            acc[j] += xv.x * w0 + xv.y * w1 + xv.z * w2 + xv.w * w3;
        }
    }
    #pragma unroll
    for (int j = 0; j < 8; ++j) {
        int node = nb + ng * 8 + j;
        if (node < n) support[(size_t)node * FDIM + f] = acc[j];
    }
}

// ---------------- aggregation: one block per node, no atomics ---------------
__global__ void __launch_bounds__(128) k_agg(const float* __restrict__ support,
                                             const int* __restrict__ offs,
                                             const int* __restrict__ sc,
                                             const float* __restrict__ dis,
                                             const float* __restrict__ bias,
                                             float* __restrict__ out, int n) {
    int i = blockIdx.x;
    int f = threadIdx.x;                            // 0..127
    int beg = offs[i], end = offs[i + 1];
    float acc = 0.f;
    int j = beg;
    for (; j + 4 <= end; j += 4) {
        int c0 = sc[j], c1 = sc[j + 1], c2 = sc[j + 2], c3 = sc[j + 3];
        float d0 = dis[c0], d1 = dis[c1], d2 = dis[c2], d3 = dis[c3];
        float s0 = support[(size_t)c0 * FDIM + f];
        float s1 = support[(size_t)c1 * FDIM + f];
        float s2 = support[(size_t)c2 * FDIM + f];
        float s3 = support[(size_t)c3 * FDIM + f];
        acc += d0 * s0 + d1 * s1 + d2 * s2 + d3 * s3;
    }
    for (; j < end; ++j) {
        int c = sc[j];
        acc += dis[c] * support[(size_t)c * FDIM + f];
    }
    out[(size_t)i * FDIM + f] = dis[i] * acc + bias[f];
}

extern "C" void kernel_launch(void* const* d_in, const int* in_sizes, int n_in,
                              void* d_out, int out_size, void* d_ws, size_t ws_size,
                              hipStream_t stream) {
    const float* x    = (const float*)d_in[0];
    const int*   ei   = (const int*)d_in[1];    // int32 on device (harness converts)
    const float* w    = (const float*)d_in[2];
    const float* bias = (const float*)d_in[3];
    float*       out  = (float*)d_out;

    int n  = in_sizes[0] / FDIM;   // 100000 nodes
    int nE = in_sizes[1] / 2;      // 3200000 edges
    const int* row = ei;
    const int* col = ei + nE;

    // workspace carve-out (ws is re-poisoned every launch; we overwrite all)
    char* ws = (char*)d_ws;
    size_t off = 0;
    auto alloc = [&](size_t bytes) -> void* {
        void* p = ws + off;
        off += (bytes + 255) & ~(size_t)255;
        return p;
    };
    float* support = (float*)alloc((size_t)n * FDIM * sizeof(float)); // 51.2 MB
    int*   cnt     = (int*)alloc((size_t)n * sizeof(int));
    int*   fill    = (int*)alloc((size_t)n * sizeof(int));
    int*   offs    = (int*)alloc((size_t)(n + 1) * sizeof(int));
    float* dis     = (float*)alloc((size_t)n * sizeof(float));
    int*   sc      = (int*)alloc((size_t)(nE + n) * sizeof(int));     // 13.2 MB

    k_init <<<(n + 255) / 256, 256, 0, stream>>>(cnt, fill, n);
    k_count<<<2048, 256, 0, stream>>>(row, cnt, nE);
    k_scan <<<1, 1024, 0, stream>>>(cnt, offs, n);
    k_dis  <<<(n + 255) / 256, 256, 0, stream>>>(cnt, dis, n);
    k_fill <<<2048, 256, 0, stream>>>(row, col, offs, fill, sc, nE, n);
    k_gemm <<<(n + 15) / 16, 256, 0, stream>>>(x, w, support, n);
    k_agg  <<<n, 128, 0, stream>>>(support, offs, sc, dis, bias, out, n);
}

// Round 4
// 683.862 us; speedup vs baseline: 1.3115x; 1.3115x over previous
//
#include <hip/hip_runtime.h>
#include <hip/hip_fp16.h>

#define FDIM 128
#define SCAN_B 1024   // elements per scan block

// ---------------- init: self-loop degree + zero fill cursors ----------------
__global__ void k_init(int* __restrict__ cnt, int* __restrict__ fill, int n) {
    int i = blockIdx.x * 256 + threadIdx.x;
    if (i < n) { cnt[i] = 1; fill[i] = 0; }
}

// ---------------- degree count over edges (row = edge_index[0]) -------------
__global__ void k_count(const int* __restrict__ row, int* __restrict__ cnt, int nE) {
    int stride = gridDim.x * blockDim.x;
    for (int e = blockIdx.x * blockDim.x + threadIdx.x; e < nE; e += stride)
        atomicAdd(&cnt[row[e]], 1);
}

// ---------------- hierarchical exclusive scan, phase 1: block sums ----------
__global__ void __launch_bounds__(1024) k_scan_reduce(const int* __restrict__ cnt,
                                                      int* __restrict__ part, int n) {
    __shared__ int sd[1024];
    int i = blockIdx.x * SCAN_B + threadIdx.x;
    int v = (i < n) ? cnt[i] : 0;
    sd[threadIdx.x] = v;
    __syncthreads();
    for (int off = 512; off > 0; off >>= 1) {
        if (threadIdx.x < off) sd[threadIdx.x] += sd[threadIdx.x + off];
        __syncthreads();
    }
    if (threadIdx.x == 0) part[blockIdx.x] = sd[0];
}

// ---------------- phase 2: exclusive scan of partials (1 block) -------------
__global__ void __launch_bounds__(128) k_scan_part(int* __restrict__ part,
                                                   int* __restrict__ offs,
                                                   int nb, int n) {
    __shared__ int sd[128];
    int v = (threadIdx.x < nb) ? part[threadIdx.x] : 0;
    sd[threadIdx.x] = v;
    __syncthreads();
    for (int off = 1; off < 128; off <<= 1) {
        int t = (threadIdx.x >= off) ? sd[threadIdx.x - off] : 0;
        __syncthreads();
        sd[threadIdx.x] += t;
        __syncthreads();
    }
    if (threadIdx.x < nb) part[threadIdx.x] = sd[threadIdx.x] - v;  // exclusive
    if (threadIdx.x == 127) offs[n] = sd[127];                      // total
}

// ---------------- phase 3: per-block scan + add partial; also dis -----------
__global__ void __launch_bounds__(1024) k_scan_final(const int* __restrict__ cnt,
                                                     const int* __restrict__ part,
                                                     int* __restrict__ offs,
                                                     float* __restrict__ dis, int n) {
    __shared__ int sd[1024];
    int i = blockIdx.x * SCAN_B + threadIdx.x;
    int v = (i < n) ? cnt[i] : 0;
    sd[threadIdx.x] = v;
    __syncthreads();
    for (int off = 1; off < 1024; off <<= 1) {
        int t = (threadIdx.x >= off) ? sd[threadIdx.x - off] : 0;
        __syncthreads();
        sd[threadIdx.x] += t;
        __syncthreads();
    }
    if (i < n) {
        offs[i] = part[blockIdx.x] + sd[threadIdx.x] - v;  // exclusive
        dis[i]  = rsqrtf((float)v);                        // v >= 1 (self loop)
    }
}

// ---------------- CSR fill: bucket col by row (includes self-loops) ---------
__global__ void k_fill(const int* __restrict__ row, const int* __restrict__ col,
                       const int* __restrict__ offs, int* __restrict__ fill,
                       int* __restrict__ sc, int nE, int n) {
    int stride = gridDim.x * blockDim.x;
    int total = nE + n;
    for (int e = blockIdx.x * blockDim.x + threadIdx.x; e < total; e += stride) {
        int r, c;
        if (e < nE) { r = row[e]; c = col[e]; }
        else        { r = e - nE; c = r; }          // self loop
        int pos = offs[r] + atomicAdd(&fill[r], 1);
        sc[pos] = c;
    }
}

// ---------------- support = dis[node] * (x @ W), stored fp16 ----------------
// Block: 256 threads = 128 features x 2 node-groups; 16 nodes per block.
__global__ void __launch_bounds__(256) k_gemm(const float* __restrict__ x,
                                              const float* __restrict__ w,
                                              const float* __restrict__ dis,
                                              __half* __restrict__ support, int n) {
    __shared__ float w_s[FDIM * FDIM];   // 64 KB
    __shared__ float x_s[16 * FDIM];     // 8 KB

    const float4* wg = reinterpret_cast<const float4*>(w);
    float4* ws4 = reinterpret_cast<float4*>(w_s);
    #pragma unroll
    for (int it = 0; it < 16; ++it)
        ws4[threadIdx.x + it * 256] = wg[threadIdx.x + it * 256];

    int nb = blockIdx.x * 16;                       // n = 100000 = 6250 * 16
    const float4* xg = reinterpret_cast<const float4*>(x + (size_t)nb * FDIM);
    float4* xs4w = reinterpret_cast<float4*>(x_s);
    #pragma unroll
    for (int it = 0; it < 2; ++it)
        xs4w[threadIdx.x + it * 256] = xg[threadIdx.x + it * 256];
    __syncthreads();

    int f  = threadIdx.x & 127;
    int ng = threadIdx.x >> 7;                      // 0..1 (8 nodes each)
    const float4* xs4 = reinterpret_cast<const float4*>(x_s);
    float acc[8] = {0, 0, 0, 0, 0, 0, 0, 0};
    for (int kg = 0; kg < 32; ++kg) {
        float w0 = w_s[(4 * kg + 0) * FDIM + f];
        float w1 = w_s[(4 * kg + 1) * FDIM + f];
        float w2 = w_s[(4 * kg + 2) * FDIM + f];
        float w3 = w_s[(4 * kg + 3) * FDIM + f];
        #pragma unroll
        for (int j = 0; j < 8; ++j) {
            float4 xv = xs4[(ng * 8 + j) * 32 + kg];   // wave-uniform -> broadcast
            acc[j] += xv.x * w0 + xv.y * w1 + xv.z * w2 + xv.w * w3;
        }
    }
    #pragma unroll
    for (int j = 0; j < 8; ++j) {
        int node = nb + ng * 8 + j;
        if (node < n)
            support[(size_t)node * FDIM + f] = __float2half(dis[node] * acc[j]);
    }
}

// ---------------- aggregation: one wave per node, half2 gathers -------------
__global__ void __launch_bounds__(64) k_agg(const __half2* __restrict__ sup2,
                                            const int* __restrict__ offs,
                                            const int* __restrict__ sc,
                                            const float* __restrict__ dis,
                                            const float* __restrict__ bias,
                                            float* __restrict__ out, int n) {
    int i  = blockIdx.x;
    int f2 = threadIdx.x;                           // 0..63 -> features 2f2,2f2+1
    int beg = offs[i], end = offs[i + 1];
    float ax = 0.f, ay = 0.f;
    int j = beg;
    for (; j + 4 <= end; j += 4) {
        int c0 = sc[j], c1 = sc[j + 1], c2 = sc[j + 2], c3 = sc[j + 3];
        float2 v0 = __half22float2(sup2[(size_t)c0 * 64 + f2]);
        float2 v1 = __half22float2(sup2[(size_t)c1 * 64 + f2]);
        float2 v2 = __half22float2(sup2[(size_t)c2 * 64 + f2]);
        float2 v3 = __half22float2(sup2[(size_t)c3 * 64 + f2]);
        ax += (v0.x + v1.x) + (v2.x + v3.x);
        ay += (v0.y + v1.y) + (v2.y + v3.y);
    }
    for (; j < end; ++j) {
        float2 v = __half22float2(sup2[(size_t)sc[j] * 64 + f2]);
        ax += v.x; ay += v.y;
    }
    float di = dis[i];
    const float2* b2 = reinterpret_cast<const float2*>(bias);
    float2 bb = b2[f2];
    float2 o;
    o.x = di * ax + bb.x;
    o.y = di * ay + bb.y;
    reinterpret_cast<float2*>(out)[(size_t)i * 64 + f2] = o;
}

extern "C" void kernel_launch(void* const* d_in, const int* in_sizes, int n_in,
                              void* d_out, int out_size, void* d_ws, size_t ws_size,
                              hipStream_t stream) {
    const float* x    = (const float*)d_in[0];
    const int*   ei   = (const int*)d_in[1];    // int32 on device (harness converts)
    const float* w    = (const float*)d_in[2];
    const float* bias = (const float*)d_in[3];
    float*       out  = (float*)d_out;

    int n  = in_sizes[0] / FDIM;   // 100000 nodes
    int nE = in_sizes[1] / 2;      // 3200000 edges
    const int* row = ei;
    const int* col = ei + nE;
    int nbscan = (n + SCAN_B - 1) / SCAN_B;     // 98 <= 128

    // workspace carve-out (ws is re-poisoned every launch; we overwrite all)
    char* ws = (char*)d_ws;
    size_t off = 0;
    auto alloc = [&](size_t bytes) -> void* {
        void* p = ws + off;
        off += (bytes + 255) & ~(size_t)255;
        return p;
    };
    __half* support = (__half*)alloc((size_t)n * FDIM * sizeof(__half)); // 25.6 MB
    int*    cnt     = (int*)alloc((size_t)n * sizeof(int));
    int*    fill    = (int*)alloc((size_t)n * sizeof(int));
    int*    offs    = (int*)alloc((size_t)(n + 1) * sizeof(int));
    int*    part    = (int*)alloc((size_t)128 * sizeof(int));
    float*  dis     = (float*)alloc((size_t)n * sizeof(float));
    int*    sc      = (int*)alloc((size_t)(nE + n) * sizeof(int));     // 13.2 MB

    k_init       <<<(n + 255) / 256, 256, 0, stream>>>(cnt, fill, n);
    k_count      <<<2048, 256, 0, stream>>>(row, cnt, nE);
    k_scan_reduce<<<nbscan, 1024, 0, stream>>>(cnt, part, n);
    k_scan_part  <<<1, 128, 0, stream>>>(part, offs, nbscan, n);
    k_scan_final <<<nbscan, 1024, 0, stream>>>(cnt, part, offs, dis, n);
    k_fill       <<<2048, 256, 0, stream>>>(row, col, offs, fill, sc, nE, n);
    k_gemm       <<<(n + 15) / 16, 256, 0, stream>>>(x, w, dis, support, n);
    k_agg        <<<n, 64, 0, stream>>>((const __half2*)support, offs, sc, dis, bias, out, n);
}